// Round 1
// baseline (392.885 us; speedup 1.0000x reference)
//
#include <hip/hip_runtime.h>
#include <hip/hip_bf16.h>

// SimRel: cosine similarity of 262144 x 256 inputs vs 64 x 256 class centroids.
// out[b][c] = dot(x_b, cls_c) / max(|x_b||cls_c|, 1e-8), 1.0 if cls_c has inf.
// Memory-bound tall-skinny GEMM done with bf16 MFMA (error ~2.5e-4 << 6.5e-3 tol).

typedef __attribute__((ext_vector_type(8))) short bf16x8;   // 8 bf16 (4 VGPRs)
typedef __attribute__((ext_vector_type(4))) float f32x4;    // MFMA C/D

#define EPS 1e-8f

__device__ __forceinline__ short f2bf(float f) {
  // fp32 -> bf16 round-to-nearest-even (preserves inf/NaN)
  union { float f; unsigned u; } v; v.f = f;
  unsigned r = v.u + 0x7fffu + ((v.u >> 16) & 1u);
  return (short)(r >> 16);
}

__global__ __launch_bounds__(256) void simrel_kernel(
    const float* __restrict__ X,    // Brows x 256
    const float* __restrict__ CLS,  // 64 x 256
    float* __restrict__ OUT)        // Brows x 64
{
  constexpr int D  = 256;
  constexpr int C  = 64;
  constexpr int SK = 264;  // padded k-stride (bf16 elems) to spread LDS banks

  __shared__ __align__(16) short Blds[C * SK];  // 33792 B
  __shared__ float cn_s[C];
  __shared__ float cinf_s[C];

  const int tid = threadIdx.x;

  // ---- prologue: stage class matrix -> LDS bf16, class norms + inf flags ----
  {
    const int c = tid >> 2;   // class 0..63
    const int q = tid & 3;    // quarter of the 256 dims
    const float4* src = (const float4*)(CLS + c * D + q * 64);
    short* dst = &Blds[c * SK + q * 64];
    float ssq = 0.f;
    int inf = 0;
#pragma unroll
    for (int i = 0; i < 16; ++i) {
      float4 v = src[i];
      ssq += v.x * v.x + v.y * v.y;
      ssq += v.z * v.z + v.w * v.w;
      inf |= (isinf(v.x) | isinf(v.y) | isinf(v.z) | isinf(v.w));
      *(short4*)(dst + i * 4) =
          make_short4(f2bf(v.x), f2bf(v.y), f2bf(v.z), f2bf(v.w));
    }
    ssq += __shfl_xor(ssq, 1);
    ssq += __shfl_xor(ssq, 2);
    inf |= __shfl_xor(inf, 1);
    inf |= __shfl_xor(inf, 2);
    if (q == 0) {
      cn_s[c]   = sqrtf(ssq);
      cinf_s[c] = inf ? 1.f : 0.f;
    }
  }
  __syncthreads();

  const int lane = tid & 63;
  const int wave = tid >> 6;   // 0..3
  const int m    = lane & 15;  // A row within tile / B col within tile
  const int quad = lane >> 4;  // 0..3 -> k-slice quad*8..+7

  const long rowbase = (long)blockIdx.x * 256 + wave * 64;

  // A fragment pointers (float4 units): row*64 + quad*2 ; k-step advances by 8
  const float4* Ap[4];
#pragma unroll
  for (int mt = 0; mt < 4; ++mt)
    Ap[mt] = (const float4*)X + (rowbase + mt * 16 + m) * 64 + quad * 2;

  // B fragment LDS pointers: Blds[(nt*16+m)][quad*8 + ks*32]
  const short* Bp[4];
#pragma unroll
  for (int nt = 0; nt < 4; ++nt)
    Bp[nt] = &Blds[(nt * 16 + m) * SK + quad * 8];

  f32x4 acc[4][4];
#pragma unroll
  for (int mt = 0; mt < 4; ++mt)
#pragma unroll
    for (int nt = 0; nt < 4; ++nt)
      acc[mt][nt] = (f32x4){0.f, 0.f, 0.f, 0.f};

  float ssqr[4] = {0.f, 0.f, 0.f, 0.f};

  // software-pipelined A loads (2 float4 per mt per k-step)
  float4 cur[8];
#pragma unroll
  for (int mt = 0; mt < 4; ++mt) {
    cur[2 * mt]     = Ap[mt][0];
    cur[2 * mt + 1] = Ap[mt][1];
  }

#pragma unroll
  for (int ks = 0; ks < 8; ++ks) {
    float4 nxt[8];
    if (ks < 7) {
#pragma unroll
      for (int mt = 0; mt < 4; ++mt) {
        nxt[2 * mt]     = Ap[mt][(ks + 1) * 8];
        nxt[2 * mt + 1] = Ap[mt][(ks + 1) * 8 + 1];
      }
    }

    bf16x8 bf[4];
#pragma unroll
    for (int nt = 0; nt < 4; ++nt)
      bf[nt] = *(const bf16x8*)(Bp[nt] + ks * 32);

#pragma unroll
    for (int mt = 0; mt < 4; ++mt) {
      float4 a0 = cur[2 * mt], a1 = cur[2 * mt + 1];
      ssqr[mt] += a0.x * a0.x + a0.y * a0.y + a0.z * a0.z + a0.w * a0.w +
                  a1.x * a1.x + a1.y * a1.y + a1.z * a1.z + a1.w * a1.w;
      bf16x8 af;
      af[0] = f2bf(a0.x); af[1] = f2bf(a0.y); af[2] = f2bf(a0.z); af[3] = f2bf(a0.w);
      af[4] = f2bf(a1.x); af[5] = f2bf(a1.y); af[6] = f2bf(a1.z); af[7] = f2bf(a1.w);
#pragma unroll
      for (int nt = 0; nt < 4; ++nt)
        acc[mt][nt] =
            __builtin_amdgcn_mfma_f32_16x16x32_bf16(af, bf[nt], acc[mt][nt], 0, 0, 0);
    }

    if (ks < 7) {
#pragma unroll
      for (int i = 0; i < 8; ++i) cur[i] = nxt[i];
    }
  }

  // ---- epilogue: norms, divide, store ----
#pragma unroll
  for (int mt = 0; mt < 4; ++mt) {
    float s = ssqr[mt];
    s += __shfl_xor(s, 16);
    s += __shfl_xor(s, 32);
    float xn = sqrtf(s);  // lane holds norm of row rowbase + mt*16 + (lane&15)
    float xnr[4];
#pragma unroll
    for (int r = 0; r < 4; ++r)
      xnr[r] = __shfl(xn, quad * 4 + r);  // norm for C/D row quad*4+r
#pragma unroll
    for (int nt = 0; nt < 4; ++nt) {
      const int n = nt * 16 + m;           // C/D col = lane&15
      const float cn  = cn_s[n];
      const bool cinf = (cinf_s[n] != 0.f);
#pragma unroll
      for (int r = 0; r < 4; ++r) {
        const long row = rowbase + mt * 16 + quad * 4 + r;
        const float denom = fmaxf(xnr[r] * cn, EPS);
        const float v =
            cinf ? 1.0f : acc[mt][nt][r] * __builtin_amdgcn_rcpf(denom);
        OUT[row * 64 + n] = v;
      }
    }
  }
}

extern "C" void kernel_launch(void* const* d_in, const int* in_sizes, int n_in,
                              void* d_out, int out_size, void* d_ws, size_t ws_size,
                              hipStream_t stream) {
  (void)n_in; (void)d_ws; (void)ws_size; (void)out_size;
  const float* X   = (const float*)d_in[0];   // inputs, fp32 B x 256
  // d_in[1] = labels (unused by the reference output)
  const float* CLS = (const float*)d_in[2];   // class_avgs, fp32 64 x 256
  float* OUT = (float*)d_out;

  const int Brows  = in_sizes[0] / 256;       // 262144
  const int blocks = Brows / 256;             // 1024 (256 rows per block)
  simrel_kernel<<<blocks, 256, 0, stream>>>(X, CLS, OUT);
}

// Round 2
// 391.154 us; speedup vs baseline: 1.0044x; 1.0044x over previous
//
#include <hip/hip_runtime.h>
#include <hip/hip_bf16.h>

// SimRel: cosine similarity of 262144 x 256 inputs vs 64 x 256 class centroids.
// out[b][c] = dot(x_b, cls_c) / max(|x_b||cls_c|, 1e-8), 1.0 if cls_c has inf.
// bf16 MFMA tall-skinny GEMM, memory-bound. k-space is PERMUTED so that each
// A global_load_dwordx4 covers full 64B lines (quad q takes floats q*4..+4 of
// each 16-float half-window); B is staged to LDS with the matching permutation.

typedef __attribute__((ext_vector_type(8))) short bf16x8;   // 8 bf16 (4 VGPRs)
typedef __attribute__((ext_vector_type(4))) float f32x4;    // MFMA C/D

#define EPS 1e-8f

__device__ __forceinline__ short f2bf(float f) {
  // fp32 -> bf16 round-to-nearest-even (preserves inf/NaN)
  union { float f; unsigned u; } v; v.f = f;
  unsigned r = v.u + 0x7fffu + ((v.u >> 16) & 1u);
  return (short)(r >> 16);
}

__global__ __launch_bounds__(256) void simrel_kernel(
    const float* __restrict__ X,    // Brows x 256
    const float* __restrict__ CLS,  // 64 x 256
    float* __restrict__ OUT)        // Brows x 64
{
  constexpr int D  = 256;
  constexpr int C  = 64;
  constexpr int SK = 264;  // padded k-stride (bf16 elems)

  __shared__ __align__(16) short Blds[C * SK];  // 33792 B
  __shared__ float cn_s[C];
  __shared__ float cinf_s[C];

  const int tid = threadIdx.x;

  // ---- prologue: stage class matrix -> LDS bf16 (k-permuted), norms, inf ----
  {
    const int c = tid >> 2;   // class 0..63
    const int q = tid & 2;    // dummy keep
    (void)q;
    const int qq = tid & 3;   // quarter of the 256 dims
    const float4* src = (const float4*)(CLS + c * D + qq * 64);
    short* dstrow = &Blds[c * SK];
    float ssq = 0.f;
    int inf = 0;
#pragma unroll
    for (int i = 0; i < 16; ++i) {
      float4 v = src[i];
      ssq += v.x * v.x + v.y * v.y;
      ssq += v.z * v.z + v.w * v.w;
      inf |= (isinf(v.x) | isinf(v.y) | isinf(v.z) | isinf(v.w));
      // global float group base within row:
      const int wabs = qq * 64 + i * 4;
      const int ks   = wabs >> 5;        // 32-float window
      const int w0   = wabs & 31;
      // permuted LDS position: quad q supplies k = q*4..+4 (half 0) and
      // 16+q*4..+4 (half 1); frag slot j runs 0..3 within each half.
      const int p0 = ks * 32 + ((w0 < 16) ? ((w0 >> 2) * 8)
                                          : (((w0 - 16) >> 2) * 8 + 4));
      *(short4*)(dstrow + p0) =
          make_short4(f2bf(v.x), f2bf(v.y), f2bf(v.z), f2bf(v.w));
    }
    ssq += __shfl_xor(ssq, 1);
    ssq += __shfl_xor(ssq, 2);
    inf |= __shfl_xor(inf, 1);
    inf |= __shfl_xor(inf, 2);
    if (qq == 0) {
      cn_s[c]   = sqrtf(ssq);
      cinf_s[c] = inf ? 1.f : 0.f;
    }
  }
  __syncthreads();

  const int lane = tid & 63;
  const int wave = tid >> 6;   // 0..3
  const int m    = lane & 15;  // A row within tile / B col within tile
  const int quad = lane >> 4;  // 0..3

  const long rowbase = (long)blockIdx.x * 256 + wave * 64;

  // A pointers (float4 units). Per k-step ks, lane loads:
  //   inst1: float4 at row*64 + ks*8 + quad        (floats ks*32 + quad*4)
  //   inst2: float4 at row*64 + ks*8 + quad + 4    (floats ks*32+16 + quad*4)
  // -> each inst: 4 quads cover one full 64B line per row. Fully coalesced.
  const float4* Ap[4];
#pragma unroll
  for (int mt = 0; mt < 4; ++mt)
    Ap[mt] = (const float4*)X + (rowbase + mt * 16 + m) * 64 + quad;

  // B fragment LDS pointers: Blds[(nt*16+m)*SK + quad*8 + ks*32]
  const short* Bp[4];
#pragma unroll
  for (int nt = 0; nt < 4; ++nt)
    Bp[nt] = &Blds[(nt * 16 + m) * SK + quad * 8];

  f32x4 acc[4][4];
#pragma unroll
  for (int mt = 0; mt < 4; ++mt)
#pragma unroll
    for (int nt = 0; nt < 4; ++nt)
      acc[mt][nt] = (f32x4){0.f, 0.f, 0.f, 0.f};

  float ssqr[4] = {0.f, 0.f, 0.f, 0.f};

  // software-pipelined A loads (2 float4 per mt per k-step)
  float4 cur[8];
#pragma unroll
  for (int mt = 0; mt < 4; ++mt) {
    cur[2 * mt]     = Ap[mt][0];
    cur[2 * mt + 1] = Ap[mt][4];
  }

#pragma unroll
  for (int ks = 0; ks < 8; ++ks) {
    float4 nxt[8];
    if (ks < 7) {
#pragma unroll
      for (int mt = 0; mt < 4; ++mt) {
        nxt[2 * mt]     = Ap[mt][(ks + 1) * 8];
        nxt[2 * mt + 1] = Ap[mt][(ks + 1) * 8 + 4];
      }
    }

    bf16x8 bf[4];
#pragma unroll
    for (int nt = 0; nt < 4; ++nt)
      bf[nt] = *(const bf16x8*)(Bp[nt] + ks * 32);

#pragma unroll
    for (int mt = 0; mt < 4; ++mt) {
      float4 a0 = cur[2 * mt], a1 = cur[2 * mt + 1];
      ssqr[mt] += a0.x * a0.x + a0.y * a0.y + a0.z * a0.z + a0.w * a0.w +
                  a1.x * a1.x + a1.y * a1.y + a1.z * a1.z + a1.w * a1.w;
      bf16x8 af;
      af[0] = f2bf(a0.x); af[1] = f2bf(a0.y); af[2] = f2bf(a0.z); af[3] = f2bf(a0.w);
      af[4] = f2bf(a1.x); af[5] = f2bf(a1.y); af[6] = f2bf(a1.z); af[7] = f2bf(a1.w);
#pragma unroll
      for (int nt = 0; nt < 4; ++nt)
        acc[mt][nt] =
            __builtin_amdgcn_mfma_f32_16x16x32_bf16(af, bf[nt], acc[mt][nt], 0, 0, 0);
    }

    if (ks < 7) {
#pragma unroll
      for (int i = 0; i < 8; ++i) cur[i] = nxt[i];
    }
  }

  // ---- epilogue: norms, divide, store ----
#pragma unroll
  for (int mt = 0; mt < 4; ++mt) {
    float s = ssqr[mt];
    s += __shfl_xor(s, 16);
    s += __shfl_xor(s, 32);
    float xn = sqrtf(s);  // lane holds norm of row rowbase + mt*16 + (lane&15)
    float xnr[4];
#pragma unroll
    for (int r = 0; r < 4; ++r)
      xnr[r] = __shfl(xn, quad * 4 + r);  // norm for C/D row quad*4+r
#pragma unroll
    for (int nt = 0; nt < 4; ++nt) {
      const int n = nt * 16 + m;           // C/D col = lane&15
      const float cn  = cn_s[n];
      const bool cinf = (cinf_s[n] != 0.f);
#pragma unroll
      for (int r = 0; r < 4; ++r) {
        const long row = rowbase + mt * 16 + quad * 4 + r;
        const float denom = fmaxf(xnr[r] * cn, EPS);
        const float v =
            cinf ? 1.0f : acc[mt][nt][r] * __builtin_amdgcn_rcpf(denom);
        OUT[row * 64 + n] = v;
      }
    }
  }
}

extern "C" void kernel_launch(void* const* d_in, const int* in_sizes, int n_in,
                              void* d_out, int out_size, void* d_ws, size_t ws_size,
                              hipStream_t stream) {
  (void)n_in; (void)d_ws; (void)ws_size; (void)out_size;
  const float* X   = (const float*)d_in[0];   // inputs, fp32 B x 256
  // d_in[1] = labels (unused by the reference output)
  const float* CLS = (const float*)d_in[2];   // class_avgs, fp32 64 x 256
  float* OUT = (float*)d_out;

  const int Brows  = in_sizes[0] / 256;       // 262144
  const int blocks = Brows / 256;             // 1024 (256 rows per block)
  simrel_kernel<<<blocks, 256, 0, stream>>>(X, CLS, OUT);
}

// Round 3
// 385.546 us; speedup vs baseline: 1.0190x; 1.0145x over previous
//
#include <hip/hip_runtime.h>
#include <hip/hip_bf16.h>
#include <math.h>

// SimRel: out[b][c] = dot(x_b, cls_c) / max(|x_b||cls_c|, 1e-8); 1.0 if cls_c has inf.
// bf16 MFMA tall-skinny GEMM. A-stream staged via async global_load_lds DMA into
// WAVE-PRIVATE double buffers (no __syncthreads in main loop), manual vmcnt waits.
// LDS = 32KB A bufs + 32KB B frags = 64KB -> 2 blocks/CU, 8 waves/CU,
// ~64KB of HBM loads in flight per CU (Little's law needs ~9KB for 6.3 TB/s).

typedef __attribute__((ext_vector_type(8))) short bf16x8;   // 8 bf16 (4 VGPRs)
typedef __attribute__((ext_vector_type(4))) float f32x4;    // MFMA C/D

#define EPS 1e-8f

__device__ __forceinline__ short f2bf(float f) {
  // fp32 -> bf16 round-to-nearest-even (preserves inf)
  union { float f; unsigned u; } v; v.f = f;
  unsigned r = v.u + 0x7fffu + ((v.u >> 16) & 1u);
  return (short)(r >> 16);
}
__device__ __forceinline__ float bf2f(short s) {
  union { float f; unsigned u; } v;
  v.u = ((unsigned)(unsigned short)s) << 16;
  return v.f;
}

// async 16B/lane global->LDS DMA; lds base must be wave-uniform, lane L lands at +L*16
__device__ __forceinline__ void dma16(const float* g, float* l) {
  __builtin_amdgcn_global_load_lds(
      (const __attribute__((address_space(1))) void*)g,
      (__attribute__((address_space(3))) void*)l, 16, 0, 0);
}

// MFMA k-slot map (both A and B): slot j of quad q <-> k = (j>>2)*16 + q*4 + (j&3)

__global__ __launch_bounds__(256) void simrel_kernel(
    const float* __restrict__ X,    // Brows x 256
    const float* __restrict__ CLS,  // 64 x 256
    float* __restrict__ OUT)        // Brows x 64
{
  // A: [wave][buf2][mti2][h2][lane64][4 floats] = 32 KB (fp32, DMA-filled)
  __shared__ __align__(16) float Abuf[4 * 2048];
  // B: [ks8][nt4][lane64][8 bf16] = 32 KB (fragment layout, read at lane*16)
  __shared__ __align__(16) short Bfrag[8 * 4 * 64 * 8];

  const int tid  = threadIdx.x;
  const int wave = tid >> 6;
  const int lane = tid & 63;
  const int m    = lane & 15;
  const int quad = lane >> 4;

  // ---- stage B (class_avgs) -> bf16 fragment layout ----
  {
    const int c  = tid >> 2;       // class 0..63
    const int qq = tid & 3;        // 64-float quarter
    const float4* src = (const float4*)CLS + c * 64 + qq * 16;
#pragma unroll
    for (int i = 0; i < 16; ++i) {
      float4 v = src[i];
      const int wabs = qq * 64 + i * 4;
      const int ks = wabs >> 5;
      const int w0 = wabs & 31;
      const int h  = w0 >> 4;
      const int qd = (w0 >> 2) & 3;
      const int lb = (qd << 4) | (c & 15);
      const int nt = c >> 4;
      *(short4*)&Bfrag[((ks * 4 + nt) * 64 + lb) * 8 + h * 4] =
          make_short4(f2bf(v.x), f2bf(v.y), f2bf(v.z), f2bf(v.w));
    }
  }
  __syncthreads();

  const size_t rowbase = (size_t)blockIdx.x * 128 + (size_t)wave * 32;

  // lane's global gather base per (mti, h); k-step adds 32 floats
  const float* gbase[2][2];
#pragma unroll
  for (int mti = 0; mti < 2; ++mti)
#pragma unroll
    for (int h = 0; h < 2; ++h)
      gbase[mti][h] = X + (rowbase + mti * 16 + m) * 256 + h * 16 + quad * 4;

  float* abase = &Abuf[wave * 2048];  // wave-private 8KB (2 buffers x 4KB)

  // prime: window 0 -> buf 0  (4 x 1KB DMA; each inst = 16 rows x 64B full lines)
#pragma unroll
  for (int mti = 0; mti < 2; ++mti)
#pragma unroll
    for (int h = 0; h < 2; ++h)
      dma16(gbase[mti][h], abase + (mti * 2 + h) * 256);

  // ---- per-wave class norms + inf flags from staged bf16 (overlaps DMA) ----
  float cnv[4]; int cflag[4];
#pragma unroll
  for (int nt = 0; nt < 4; ++nt) {
    float s = 0.f;
#pragma unroll
    for (int ks = 0; ks < 8; ++ks) {
      bf16x8 b = *(const bf16x8*)&Bfrag[((ks * 4 + nt) * 64 + lane) * 8];
#pragma unroll
      for (int j = 0; j < 8; ++j) { float f = bf2f(b[j]); s += f * f; }
    }
    s += __shfl_xor(s, 16);
    s += __shfl_xor(s, 32);
    cflag[nt] = !isfinite(s);   // inf in class -> sentinel 1.0
    cnv[nt]   = sqrtf(s);
  }

  f32x4 acc[2][4];
#pragma unroll
  for (int mti = 0; mti < 2; ++mti)
#pragma unroll
    for (int nt = 0; nt < 4; ++nt)
      acc[mti][nt] = (f32x4){0.f, 0.f, 0.f, 0.f};
  float ssqr[2] = {0.f, 0.f};

#pragma unroll
  for (int ks = 0; ks < 8; ++ks) {
    if (ks < 7) {
      // issue window ks+1 into the other buffer, then wait for window ks
      const int nb = (ks + 1) & 1;
#pragma unroll
      for (int mti = 0; mti < 2; ++mti)
#pragma unroll
        for (int h = 0; h < 2; ++h)
          dma16(gbase[mti][h] + (ks + 1) * 32, abase + (nb * 4 + mti * 2 + h) * 256);
      asm volatile("s_waitcnt vmcnt(4)" ::: "memory");
    } else {
      asm volatile("s_waitcnt vmcnt(0)" ::: "memory");
    }
    const int cb = ks & 1;

    bf16x8 bw[4];
#pragma unroll
    for (int nt = 0; nt < 4; ++nt)
      bw[nt] = *(const bf16x8*)&Bfrag[((ks * 4 + nt) * 64 + lane) * 8];

#pragma unroll
    for (int mti = 0; mti < 2; ++mti) {
      float4 a0 = *(const float4*)(abase + (cb * 4 + mti * 2 + 0) * 256 + lane * 4);
      float4 a1 = *(const float4*)(abase + (cb * 4 + mti * 2 + 1) * 256 + lane * 4);
      ssqr[mti] += a0.x * a0.x + a0.y * a0.y + a0.z * a0.z + a0.w * a0.w +
                   a1.x * a1.x + a1.y * a1.y + a1.z * a1.z + a1.w * a1.w;
      bf16x8 af;
      af[0] = f2bf(a0.x); af[1] = f2bf(a0.y); af[2] = f2bf(a0.z); af[3] = f2bf(a0.w);
      af[4] = f2bf(a1.x); af[5] = f2bf(a1.y); af[6] = f2bf(a1.z); af[7] = f2bf(a1.w);
#pragma unroll
      for (int nt = 0; nt < 4; ++nt)
        acc[mti][nt] =
            __builtin_amdgcn_mfma_f32_16x16x32_bf16(af, bw[nt], acc[mti][nt], 0, 0, 0);
    }
  }

  // ---- epilogue: norms, divide, store ----
#pragma unroll
  for (int mti = 0; mti < 2; ++mti) {
    float s = ssqr[mti];
    s += __shfl_xor(s, 16);
    s += __shfl_xor(s, 32);
    float xn = sqrtf(s);  // norm of row rowbase + mti*16 + m
    float xnr[4];
#pragma unroll
    for (int r = 0; r < 4; ++r)
      xnr[r] = __shfl(xn, quad * 4 + r);  // norm for C/D row quad*4+r
#pragma unroll
    for (int nt = 0; nt < 4; ++nt) {
      const int n = nt * 16 + m;          // C/D col = lane&15
#pragma unroll
      for (int r = 0; r < 4; ++r) {
        const size_t row = rowbase + mti * 16 + quad * 4 + r;
        const float d = fmaxf(xnr[r] * cnv[nt], EPS);
        const float v =
            cflag[nt] ? 1.0f : acc[mti][nt][r] * __builtin_amdgcn_rcpf(d);
        OUT[row * 64 + n] = v;
      }
    }
  }
}

extern "C" void kernel_launch(void* const* d_in, const int* in_sizes, int n_in,
                              void* d_out, int out_size, void* d_ws, size_t ws_size,
                              hipStream_t stream) {
  (void)n_in; (void)d_ws; (void)ws_size; (void)out_size;
  const float* X   = (const float*)d_in[0];   // inputs, fp32 B x 256
  // d_in[1] = labels (unused by the reference output)
  const float* CLS = (const float*)d_in[2];   // class_avgs, fp32 64 x 256
  float* OUT = (float*)d_out;

  const int Brows  = in_sizes[0] / 256;       // 262144
  const int blocks = Brows / 128;             // 2048 (128 rows per block)
  simrel_kernel<<<blocks, 256, 0, stream>>>(X, CLS, OUT);
}